// Round 1
// baseline (14985.245 us; speedup 1.0000x reference)
//
#include <hip/hip_runtime.h>

#define B 128
#define C 32
#define HH 16
#define V 4096
#define TT 8

// ---------------- helpers ----------------

__device__ __forceinline__ float cubicw(float t) {
    // PyTorch bicubic kernel, a = -0.75
    float at = fabsf(t);
    float at2 = at * at, at3 = at2 * at;
    if (at <= 1.f) return 1.25f * at3 - 2.25f * at2 + 1.f;
    if (at < 2.f)  return -0.75f * at3 + 3.75f * at2 - 6.f * at + 3.f;
    return 0.f;
}

// ---------------- kernels ----------------

__global__ void init_kernel(const float* __restrict__ feat, float* __restrict__ f_rest,
                            float* __restrict__ f_hat) {
    int i = blockIdx.x * 256 + threadIdx.x;
    if (i < B * C * HH * HH) { f_rest[i] = feat[i]; f_hat[i] = 0.f; }
}

__global__ void c2_kernel(const float* __restrict__ cb, double* __restrict__ c2) {
    int v = blockIdx.x * 256 + threadIdx.x;
    if (v < V) {
        const float* p = cb + v * C;
        double s = 0.0;
        #pragma unroll
        for (int j = 0; j < C; ++j) { double d = (double)p[j]; s = fma(d, d, s); }
        c2[v] = s;
    }
}

// area (adaptive-avg-pool) downsample: [B,C,16,16] -> [B,C,pn,pn]
__global__ void area_down_kernel(const float* __restrict__ src, float* __restrict__ dst, int pn) {
    int i = blockIdx.x * blockDim.x + threadIdx.x;
    int npx = pn * pn;
    int total = B * C * npx;
    if (i >= total) return;
    int x = i % pn, y = (i / pn) % pn, bc = i / npx;
    int sh = (y * HH) / pn, eh = ((y + 1) * HH + pn - 1) / pn;
    int sw = (x * HH) / pn, ew = ((x + 1) * HH + pn - 1) / pn;
    const float* p = src + bc * (HH * HH);
    float s = 0.f;
    for (int yy = sh; yy < eh; ++yy)
        for (int xx = sw; xx < ew; ++xx) s += p[yy * HH + xx];
    dst[i] = s * (1.f / (float)((eh - sh) * (ew - sw)));
}

// nearest-codebook quantization; writes hard embedding h[B,C,pn,pn]
__global__ __launch_bounds__(256) void quantize_kernel(
    const float* __restrict__ z, const float* __restrict__ cb,
    const double* __restrict__ c2, float* __restrict__ h, int pn)
{
    int npx = pn * pn;
    int tid = threadIdx.x;
    int tok0 = blockIdx.x * TT;

    __shared__ double zs[TT][C];
    {
        int t = tid >> 5, c = tid & 31;
        int tok = tok0 + t;
        int b = tok / npx, n = tok - b * npx;
        zs[t][c] = (double)z[(b * C + c) * npx + n];
    }
    __syncthreads();

    double best[TT]; int bidx[TT];
    #pragma unroll
    for (int t = 0; t < TT; ++t) { best[t] = 1e300; bidx[t] = 0x7fffffff; }

    #pragma unroll 1
    for (int m = 0; m < 8; ++m) {
        int v0 = tid + (2 * m) * 256;
        int v1 = tid + (2 * m + 1) * 256;
        float cc0[C], cc1[C];
        const float4* p0 = reinterpret_cast<const float4*>(cb + v0 * C);
        const float4* p1 = reinterpret_cast<const float4*>(cb + v1 * C);
        #pragma unroll
        for (int qq = 0; qq < 8; ++qq) {
            float4 f0 = p0[qq], f1 = p1[qq];
            cc0[4*qq+0] = f0.x; cc0[4*qq+1] = f0.y; cc0[4*qq+2] = f0.z; cc0[4*qq+3] = f0.w;
            cc1[4*qq+0] = f1.x; cc1[4*qq+1] = f1.y; cc1[4*qq+2] = f1.z; cc1[4*qq+3] = f1.w;
        }
        double acc0[TT], acc1[TT];
        #pragma unroll
        for (int t = 0; t < TT; ++t) { acc0[t] = 0.0; acc1[t] = 0.0; }
        #pragma unroll
        for (int j2 = 0; j2 < 16; ++j2) {
            double a0 = (double)cc0[2*j2], a1 = (double)cc0[2*j2+1];
            double b0 = (double)cc1[2*j2], b1 = (double)cc1[2*j2+1];
            #pragma unroll
            for (int t = 0; t < TT; ++t) {
                double2 zz = *reinterpret_cast<const double2*>(&zs[t][2*j2]);
                acc0[t] = fma(a1, zz.y, fma(a0, zz.x, acc0[t]));
                acc1[t] = fma(b1, zz.y, fma(b0, zz.x, acc1[t]));
            }
        }
        double cv0 = c2[v0], cv1 = c2[v1];
        #pragma unroll
        for (int t = 0; t < TT; ++t) {
            double s0 = fma(-2.0, acc0[t], cv0);
            double s1 = fma(-2.0, acc1[t], cv1);
            if (s0 < best[t] || (s0 == best[t] && v0 < bidx[t])) { best[t] = s0; bidx[t] = v0; }
            if (s1 < best[t] || (s1 == best[t] && v1 < bidx[t])) { best[t] = s1; bidx[t] = v1; }
        }
    }

    __shared__ double ss[TT][256];
    __shared__ int sidx[TT][256];
    #pragma unroll
    for (int t = 0; t < TT; ++t) { ss[t][tid] = best[t]; sidx[t][tid] = bidx[t]; }
    __syncthreads();
    for (int s = 128; s > 0; s >>= 1) {
        if (tid < s) {
            #pragma unroll
            for (int t = 0; t < TT; ++t) {
                double o = ss[t][tid + s]; int oi = sidx[t][tid + s];
                double me = ss[t][tid];    int mi = sidx[t][tid];
                if (o < me || (o == me && oi < mi)) { ss[t][tid] = o; sidx[t][tid] = oi; }
            }
        }
        __syncthreads();
    }
    {
        int t = tid >> 5, c = tid & 31;
        int tok = tok0 + t;
        int b = tok / npx, n = tok - b * npx;
        int vb = sidx[t][0];
        h[(b * C + c) * npx + n] = cb[vb * C + c];
    }
}

// bicubic upsample [B,C,pn,pn] -> [B,C,16,16]
__global__ void bicubic_up_kernel(const float* __restrict__ h, float* __restrict__ hup, int pn) {
    int i = blockIdx.x * blockDim.x + threadIdx.x;
    if (i >= B * C * HH * HH) return;
    int q = i & 15, p = (i >> 4) & 15, bc = i >> 8;
    float scale = (float)pn * (1.f / 16.f);
    float srcp = (p + 0.5f) * scale - 0.5f;
    float srcq = (q + 0.5f) * scale - 0.5f;
    int fp_ = (int)floorf(srcp), fq_ = (int)floorf(srcq);
    float tp = srcp - (float)fp_, tq = srcq - (float)fq_;
    float wp[4], wq[4];
    #pragma unroll
    for (int k = 0; k < 4; ++k) { wp[k] = cubicw((float)(k - 1) - tp); wq[k] = cubicw((float)(k - 1) - tq); }
    const float* src = h + bc * pn * pn;
    float s = 0.f;
    #pragma unroll
    for (int kp = 0; kp < 4; ++kp) {
        int ip = min(max(fp_ + kp - 1, 0), pn - 1);
        float sr = 0.f;
        #pragma unroll
        for (int kq = 0; kq < 4; ++kq) {
            int iq = min(max(fq_ + kq - 1, 0), pn - 1);
            sr = fmaf(wq[kq], src[ip * pn + iq], sr);
        }
        s = fmaf(wp[kp], sr, s);
    }
    hup[i] = s;
}

// 3x3 SAME conv (32->32 ch) + bias, blend 0.5/0.5, update f_hat += , f_rest -=
__global__ __launch_bounds__(256) void conv_update_kernel(
    const float* __restrict__ hup, const float* __restrict__ w,
    const float* __restrict__ bias, float* __restrict__ f_hat, float* __restrict__ f_rest)
{
    int b = blockIdx.x >> 1, og = (blockIdx.x & 1) * 16;
    int tid = threadIdx.x;
    __shared__ float hs[C][256];
    #pragma unroll
    for (int i = 0; i < C; ++i) hs[i][tid] = hup[(b * C + i) * 256 + tid];
    __syncthreads();
    int p = tid >> 4, q = tid & 15;
    float acc[16];
    #pragma unroll
    for (int o = 0; o < 16; ++o) acc[o] = bias[og + o];
    for (int i = 0; i < C; ++i) {
        float v[9];
        #pragma unroll
        for (int dy = 0; dy < 3; ++dy)
            #pragma unroll
            for (int dx = 0; dx < 3; ++dx) {
                int pp = p + dy - 1, qq = q + dx - 1;
                bool in = (pp >= 0) & (pp < 16) & (qq >= 0) & (qq < 16);
                v[dy * 3 + dx] = in ? hs[i][pp * 16 + qq] : 0.f;
            }
        #pragma unroll
        for (int o = 0; o < 16; ++o) {
            const float* wp = w + ((og + o) * C + i) * 9;
            #pragma unroll
            for (int k = 0; k < 9; ++k) acc[o] = fmaf(wp[k], v[k], acc[o]);
        }
    }
    #pragma unroll
    for (int o = 0; o < 16; ++o) {
        int idx = (b * C + og + o) * 256 + tid;
        float hu = hup[idx];
        float blend = 0.5f * hu + 0.5f * acc[o];
        f_hat[idx] += blend;
        f_rest[idx] -= blend;
    }
}

// context: area-downsample f_hat to pn x pn, write transposed slice into out [B,680,C]
__global__ void context_kernel(const float* __restrict__ f_hat, float* __restrict__ out,
                               int pn, int off) {
    int i = blockIdx.x * blockDim.x + threadIdx.x;
    int npx = pn * pn;
    if (i >= B * npx * C) return;
    int c = i & 31;
    int n = (i >> 5) % npx;
    int b = i / (npx * C);
    float val;
    if (pn == HH) {
        val = f_hat[(b * C + c) * 256 + n];
    } else {
        int y = n / pn, x = n - y * pn;
        int sh = (y * HH) / pn, eh = ((y + 1) * HH + pn - 1) / pn;
        int sw = (x * HH) / pn, ew = ((x + 1) * HH + pn - 1) / pn;
        const float* p = f_hat + (b * C + c) * (HH * HH);
        float s = 0.f;
        for (int yy = sh; yy < eh; ++yy)
            for (int xx = sw; xx < ew; ++xx) s += p[yy * HH + xx];
        val = s * (1.f / (float)((eh - sh) * (ew - sw)));
    }
    out[(b * 680 + off + n) * C + c] = val;
}

// ---------------- launch ----------------

extern "C" void kernel_launch(void* const* d_in, const int* in_sizes, int n_in,
                              void* d_out, int out_size, void* d_ws, size_t ws_size,
                              hipStream_t stream) {
    const float* feat = (const float*)d_in[0];
    const float* cb   = (const float*)d_in[1];
    const float* phiw = (const float*)d_in[2];
    const float* phib = (const float*)d_in[3];
    float* out = (float*)d_out;
    float* wsf = (float*)d_ws;

    const int NE = B * C * HH * HH; // 1048576
    float* f_rest = wsf;
    float* f_hat  = wsf + NE;
    float* zbuf   = wsf + 2 * NE;   // reused as h_up buffer too
    float* hbuf   = wsf + 3 * NE;
    double* c2    = (double*)(wsf + 4 * NE);

    static const int PN_[10]  = {1, 2, 3, 4, 5, 6, 8, 10, 13, 16};
    static const int PI_[10]  = {0, 0, 1, 1, 1, 2, 2, 2, 3, 3};
    static const int OFF_[10] = {0, 1, 5, 14, 30, 55, 91, 155, 255, 424};

    hipLaunchKernelGGL(init_kernel, dim3((NE + 255) / 256), dim3(256), 0, stream,
                       feat, f_rest, f_hat);
    hipLaunchKernelGGL(c2_kernel, dim3(V / 256), dim3(256), 0, stream, cb, c2);

    for (int si = 0; si < 10; ++si) {
        int pn = PN_[si], npx = pn * pn;
        const float* zptr;
        if (si < 9) {
            int total = B * C * npx;
            hipLaunchKernelGGL(area_down_kernel, dim3((total + 255) / 256), dim3(256), 0, stream,
                               f_rest, zbuf, pn);
            zptr = zbuf;
        } else {
            zptr = f_rest;
        }
        hipLaunchKernelGGL(quantize_kernel, dim3(B * npx / TT), dim3(256), 0, stream,
                           zptr, cb, c2, hbuf, pn);
        const float* hupptr;
        if (si < 9) {
            hipLaunchKernelGGL(bicubic_up_kernel, dim3(NE / 256), dim3(256), 0, stream,
                               hbuf, zbuf, pn);
            hupptr = zbuf;
        } else {
            hupptr = hbuf;
        }
        hipLaunchKernelGGL(conv_update_kernel, dim3(B * 2), dim3(256), 0, stream,
                           hupptr, phiw + PI_[si] * C * C * 9, phib + PI_[si] * C, f_hat, f_rest);
        int ctot = B * npx * C;
        hipLaunchKernelGGL(context_kernel, dim3((ctot + 255) / 256), dim3(256), 0, stream,
                           f_hat, out, pn, OFF_[si]);
    }
}

// Round 2
// 1661.172 us; speedup vs baseline: 9.0209x; 9.0209x over previous
//
#include <hip/hip_runtime.h>

#define B 128
#define C 32
#define HH 16
#define V 4096
#define CHUNK 128

// ---------------- helpers ----------------

__device__ __forceinline__ float cubicw(float t) {
    // PyTorch bicubic kernel, a = -0.75
    float at = fabsf(t);
    float at2 = at * at, at3 = at2 * at;
    if (at <= 1.f) return 1.25f * at3 - 2.25f * at2 + 1.f;
    if (at < 2.f)  return -0.75f * at3 + 3.75f * at2 - 6.f * at + 3.f;
    return 0.f;
}

// ---------------- kernels ----------------

__global__ void init_kernel(const float* __restrict__ feat, float* __restrict__ f_rest,
                            float* __restrict__ f_hat) {
    int i = blockIdx.x * 256 + threadIdx.x;
    if (i < B * C * HH * HH) { f_rest[i] = feat[i]; f_hat[i] = 0.f; }
}

__global__ void c2_kernel(const float* __restrict__ cb, double* __restrict__ c2) {
    int v = blockIdx.x * 256 + threadIdx.x;
    if (v < V) {
        const float* p = cb + v * C;
        double s = 0.0;
        #pragma unroll
        for (int j = 0; j < C; ++j) { double d = (double)p[j]; s = fma(d, d, s); }
        c2[v] = s;
    }
}

// area (adaptive-avg-pool) downsample: [B,C,16,16] -> [B,C,pn,pn]
__global__ void area_down_kernel(const float* __restrict__ src, float* __restrict__ dst, int pn) {
    int i = blockIdx.x * blockDim.x + threadIdx.x;
    int npx = pn * pn;
    int total = B * C * npx;
    if (i >= total) return;
    int x = i % pn, y = (i / pn) % pn, bc = i / npx;
    int sh = (y * HH) / pn, eh = ((y + 1) * HH + pn - 1) / pn;
    int sw = (x * HH) / pn, ew = ((x + 1) * HH + pn - 1) / pn;
    const float* p = src + bc * (HH * HH);
    float s = 0.f;
    for (int yy = sh; yy < eh; ++yy)
        for (int xx = sw; xx < ew; ++xx) s += p[yy * HH + xx];
    dst[i] = s * (1.f / (float)((eh - sh) * (ew - sw)));
}

// ---- quantization: token-per-thread scan over a codebook segment ----
// grid = nblk_tok * nseg blocks of 256 threads.
// block = (seg, tb): seg = blockIdx.x / nblk_tok, tb = blockIdx.x % nblk_tok
// Each thread owns one token, scans codes [seg*cps, (seg+1)*cps) in fp64,
// codebook chunk staged in LDS as fp64 (broadcast reads).
__global__ __launch_bounds__(256) void quantize_scan_kernel(
    const float* __restrict__ z, const float* __restrict__ cb,
    const double* __restrict__ c2, double* __restrict__ pscore,
    int* __restrict__ pidx, int pn, int nseg, int nblk_tok)
{
    int npx = pn * pn;
    int total = B * npx;
    int tid = threadIdx.x;
    int tb  = blockIdx.x % nblk_tok;
    int seg = blockIdx.x / nblk_tok;
    int tok = tb * 256 + tid;
    int tokc = min(tok, total - 1);
    int b = tokc / npx, n = tokc - b * npx;

    double zd[C];
    #pragma unroll
    for (int c = 0; c < C; ++c) zd[c] = (double)z[(b * C + c) * npx + n];

    int cps = V / nseg;
    int seg_base = seg * cps;

    __shared__ alignas(16) double lcb[CHUNK * C];
    __shared__ double lc2[CHUNK];

    double best = 1e300; int bi = 0x7fffffff;

    for (int ch = 0; ch < cps; ch += CHUNK) {
        __syncthreads();
        const float* src = cb + (seg_base + ch) * C;
        // stage: e = tid + k*256 -> LDS bank = (2e)%32, 2-way (free); global reads coalesced
        #pragma unroll
        for (int k = 0; k < (CHUNK * C) / 256; ++k) {
            int e = tid + k * 256;
            lcb[e] = (double)src[e];
        }
        if (tid < CHUNK) lc2[tid] = c2[seg_base + ch + tid];
        __syncthreads();

        for (int v = 0; v < CHUNK; ++v) {
            double acc = 0.0;
            #pragma unroll
            for (int j = 0; j < C; j += 2) {
                double2 cc = *reinterpret_cast<const double2*>(&lcb[v * C + j]);
                acc = fma(cc.y, zd[j + 1], fma(cc.x, zd[j], acc));
            }
            double s = fma(-2.0, acc, lc2[v]);
            int vg = seg_base + ch + v;
            if (s < best || (s == best && vg < bi)) { best = s; bi = vg; }
        }
    }

    if (tok < total) {
        int TP = nblk_tok * 256;
        pscore[seg * TP + tok] = best;
        pidx [seg * TP + tok] = bi;
    }
}

// combine per-segment argmins, gather codebook row into h[B,C,pn,pn]
__global__ __launch_bounds__(256) void quantize_combine_kernel(
    const double* __restrict__ pscore, const int* __restrict__ pidx,
    const float* __restrict__ cb, float* __restrict__ h,
    int pn, int nseg, int nblk_tok)
{
    int npx = pn * pn;
    int total = B * npx;
    int tok = blockIdx.x * 256 + threadIdx.x;
    if (tok >= total) return;
    int TP = nblk_tok * 256;
    double best = pscore[tok]; int bi = pidx[tok];
    for (int s = 1; s < nseg; ++s) {
        double sc = pscore[s * TP + tok]; int id = pidx[s * TP + tok];
        if (sc < best || (sc == best && id < bi)) { best = sc; bi = id; }
    }
    int b = tok / npx, n = tok - b * npx;
    const float* cp = cb + bi * C;
    #pragma unroll
    for (int c = 0; c < C; ++c) h[(b * C + c) * npx + n] = cp[c];
}

// bicubic upsample [B,C,pn,pn] -> [B,C,16,16]
__global__ void bicubic_up_kernel(const float* __restrict__ h, float* __restrict__ hup, int pn) {
    int i = blockIdx.x * blockDim.x + threadIdx.x;
    if (i >= B * C * HH * HH) return;
    int q = i & 15, p = (i >> 4) & 15, bc = i >> 8;
    float scale = (float)pn * (1.f / 16.f);
    float srcp = (p + 0.5f) * scale - 0.5f;
    float srcq = (q + 0.5f) * scale - 0.5f;
    int fp_ = (int)floorf(srcp), fq_ = (int)floorf(srcq);
    float tp = srcp - (float)fp_, tq = srcq - (float)fq_;
    float wp[4], wq[4];
    #pragma unroll
    for (int k = 0; k < 4; ++k) { wp[k] = cubicw((float)(k - 1) - tp); wq[k] = cubicw((float)(k - 1) - tq); }
    const float* src = h + bc * pn * pn;
    float s = 0.f;
    #pragma unroll
    for (int kp = 0; kp < 4; ++kp) {
        int ip = min(max(fp_ + kp - 1, 0), pn - 1);
        float sr = 0.f;
        #pragma unroll
        for (int kq = 0; kq < 4; ++kq) {
            int iq = min(max(fq_ + kq - 1, 0), pn - 1);
            sr = fmaf(wq[kq], src[ip * pn + iq], sr);
        }
        s = fmaf(wp[kp], sr, s);
    }
    hup[i] = s;
}

// 3x3 SAME conv (32->32 ch) + bias, blend 0.5/0.5, update f_hat += , f_rest -=
__global__ __launch_bounds__(256) void conv_update_kernel(
    const float* __restrict__ hup, const float* __restrict__ w,
    const float* __restrict__ bias, float* __restrict__ f_hat, float* __restrict__ f_rest)
{
    int b = blockIdx.x >> 1, og = (blockIdx.x & 1) * 16;
    int tid = threadIdx.x;
    __shared__ float hs[C][256];
    #pragma unroll
    for (int i = 0; i < C; ++i) hs[i][tid] = hup[(b * C + i) * 256 + tid];
    __syncthreads();
    int p = tid >> 4, q = tid & 15;
    float acc[16];
    #pragma unroll
    for (int o = 0; o < 16; ++o) acc[o] = bias[og + o];
    for (int i = 0; i < C; ++i) {
        float v[9];
        #pragma unroll
        for (int dy = 0; dy < 3; ++dy)
            #pragma unroll
            for (int dx = 0; dx < 3; ++dx) {
                int pp = p + dy - 1, qq = q + dx - 1;
                bool in = (pp >= 0) & (pp < 16) & (qq >= 0) & (qq < 16);
                v[dy * 3 + dx] = in ? hs[i][pp * 16 + qq] : 0.f;
            }
        #pragma unroll
        for (int o = 0; o < 16; ++o) {
            const float* wp = w + ((og + o) * C + i) * 9;
            #pragma unroll
            for (int k = 0; k < 9; ++k) acc[o] = fmaf(wp[k], v[k], acc[o]);
        }
    }
    #pragma unroll
    for (int o = 0; o < 16; ++o) {
        int idx = (b * C + og + o) * 256 + tid;
        float hu = hup[idx];
        float blend = 0.5f * hu + 0.5f * acc[o];
        f_hat[idx] += blend;
        f_rest[idx] -= blend;
    }
}

// context: area-downsample f_hat to pn x pn, write transposed slice into out [B,680,C]
__global__ void context_kernel(const float* __restrict__ f_hat, float* __restrict__ out,
                               int pn, int off) {
    int i = blockIdx.x * blockDim.x + threadIdx.x;
    int npx = pn * pn;
    if (i >= B * npx * C) return;
    int c = i & 31;
    int n = (i >> 5) % npx;
    int b = i / (npx * C);
    float val;
    if (pn == HH) {
        val = f_hat[(b * C + c) * 256 + n];
    } else {
        int y = n / pn, x = n - y * pn;
        int sh = (y * HH) / pn, eh = ((y + 1) * HH + pn - 1) / pn;
        int sw = (x * HH) / pn, ew = ((x + 1) * HH + pn - 1) / pn;
        const float* p = f_hat + (b * C + c) * (HH * HH);
        float s = 0.f;
        for (int yy = sh; yy < eh; ++yy)
            for (int xx = sw; xx < ew; ++xx) s += p[yy * HH + xx];
        val = s * (1.f / (float)((eh - sh) * (ew - sw)));
    }
    out[(b * 680 + off + n) * C + c] = val;
}

// ---------------- launch ----------------

extern "C" void kernel_launch(void* const* d_in, const int* in_sizes, int n_in,
                              void* d_out, int out_size, void* d_ws, size_t ws_size,
                              hipStream_t stream) {
    const float* feat = (const float*)d_in[0];
    const float* cb   = (const float*)d_in[1];
    const float* phiw = (const float*)d_in[2];
    const float* phib = (const float*)d_in[3];
    float* out = (float*)d_out;
    float* wsf = (float*)d_ws;

    const int NE = B * C * HH * HH; // 1048576
    float* f_rest = wsf;
    float* f_hat  = wsf + NE;
    float* zbuf   = wsf + 2 * NE;   // reused as h_up buffer too
    float* hbuf   = wsf + 3 * NE;
    char*  tail   = (char*)(wsf + 4 * NE);
    double* c2     = (double*)tail;                       // 32 KB
    double* pscore = (double*)(tail + (32 << 10));        // 2 MB (262144 doubles max)
    int*    pidx   = (int*)   (tail + (32 << 10) + (2 << 20)); // 1 MB

    static const int PN_[10]   = {1, 2, 3, 4, 5, 6, 8, 10, 13, 16};
    static const int PI_[10]   = {0, 0, 1, 1, 1, 2, 2, 2, 3, 3};
    static const int OFF_[10]  = {0, 1, 5, 14, 30, 55, 91, 155, 255, 424};
    static const int NSEG_[10] = {32, 32, 32, 32, 32, 32, 32, 16, 8, 8};

    hipLaunchKernelGGL(init_kernel, dim3((NE + 255) / 256), dim3(256), 0, stream,
                       feat, f_rest, f_hat);
    hipLaunchKernelGGL(c2_kernel, dim3(V / 256), dim3(256), 0, stream, cb, c2);

    for (int si = 0; si < 10; ++si) {
        int pn = PN_[si], npx = pn * pn;
        int tokens = B * npx;
        int nblk_tok = (tokens + 255) / 256;
        int nseg = NSEG_[si];

        const float* zptr;
        if (si < 9) {
            int total = B * C * npx;
            hipLaunchKernelGGL(area_down_kernel, dim3((total + 255) / 256), dim3(256), 0, stream,
                               f_rest, zbuf, pn);
            zptr = zbuf;
        } else {
            zptr = f_rest;
        }

        hipLaunchKernelGGL(quantize_scan_kernel, dim3(nblk_tok * nseg), dim3(256), 0, stream,
                           zptr, cb, c2, pscore, pidx, pn, nseg, nblk_tok);
        hipLaunchKernelGGL(quantize_combine_kernel, dim3(nblk_tok), dim3(256), 0, stream,
                           pscore, pidx, cb, hbuf, pn, nseg, nblk_tok);

        const float* hupptr;
        if (si < 9) {
            hipLaunchKernelGGL(bicubic_up_kernel, dim3(NE / 256), dim3(256), 0, stream,
                               hbuf, zbuf, pn);
            hupptr = zbuf;
        } else {
            hupptr = hbuf;
        }
        hipLaunchKernelGGL(conv_update_kernel, dim3(B * 2), dim3(256), 0, stream,
                           hupptr, phiw + PI_[si] * C * C * 9, phib + PI_[si] * C, f_hat, f_rest);
        int ctot = B * npx * C;
        hipLaunchKernelGGL(context_kernel, dim3((ctot + 255) / 256), dim3(256), 0, stream,
                           f_hat, out, pn, OFF_[si]);
    }
}

// Round 3
// 1381.918 us; speedup vs baseline: 10.8438x; 1.2021x over previous
//
#include <hip/hip_runtime.h>

#define B 128
#define C 32
#define HH 16
#define V 4096
#define CHUNK 128

// ---------------- helpers ----------------

__device__ __forceinline__ float cubicw(float t) {
    // PyTorch bicubic kernel, a = -0.75
    float at = fabsf(t);
    float at2 = at * at, at3 = at2 * at;
    if (at <= 1.f) return 1.25f * at3 - 2.25f * at2 + 1.f;
    if (at < 2.f)  return -0.75f * at3 + 3.75f * at2 - 6.f * at + 3.f;
    return 0.f;
}

// ---------------- kernels ----------------

__global__ void init_kernel(const float* __restrict__ feat, float* __restrict__ f_rest,
                            float* __restrict__ f_hat) {
    int i = blockIdx.x * 256 + threadIdx.x;
    if (i < B * C * HH * HH) { f_rest[i] = feat[i]; f_hat[i] = 0.f; }
}

__global__ void c2_kernel(const float* __restrict__ cb, double* __restrict__ c2) {
    int v = blockIdx.x * 256 + threadIdx.x;
    if (v < V) {
        const float* p = cb + v * C;
        double s = 0.0;
        #pragma unroll
        for (int j = 0; j < C; ++j) { double d = (double)p[j]; s = fma(d, d, s); }
        c2[v] = s;
    }
}

// area (adaptive-avg-pool) downsample: [B,C,16,16] -> [B,C,pn,pn] (stage-0 z only)
__global__ void area_down_kernel(const float* __restrict__ src, float* __restrict__ dst, int pn) {
    int i = blockIdx.x * blockDim.x + threadIdx.x;
    int npx = pn * pn;
    int total = B * C * npx;
    if (i >= total) return;
    int x = i % pn, y = (i / pn) % pn, bc = i / npx;
    int sh = (y * HH) / pn, eh = ((y + 1) * HH + pn - 1) / pn;
    int sw = (x * HH) / pn, ew = ((x + 1) * HH + pn - 1) / pn;
    const float* p = src + bc * (HH * HH);
    float s = 0.f;
    for (int yy = sh; yy < eh; ++yy)
        for (int xx = sw; xx < ew; ++xx) s += p[yy * HH + xx];
    dst[i] = s * (1.f / (float)((eh - sh) * (ew - sw)));
}

// ---- quantization scan: TPT tokens per thread over a codebook segment ----
template<int TPT>
__global__ __launch_bounds__(256) void quantize_scan_kernel(
    const float* __restrict__ z, const float* __restrict__ cb,
    const double* __restrict__ c2, double* __restrict__ pscore,
    int* __restrict__ pidx, int npx, int nseg, int nblk_tok)
{
    int total = B * npx;
    int tid = threadIdx.x;
    int tb  = blockIdx.x % nblk_tok;
    int seg = blockIdx.x / nblk_tok;
    int cps = V / nseg;
    int seg_base = seg * cps;

    double zd[TPT][C];
    int tokv[TPT];
    #pragma unroll
    for (int t = 0; t < TPT; ++t) {
        int tok = tb * (256 * TPT) + t * 256 + tid;
        tokv[t] = tok;
        int tokc = min(tok, total - 1);
        int b = tokc / npx, n = tokc - b * npx;
        #pragma unroll
        for (int c = 0; c < C; ++c) zd[t][c] = (double)z[(b * C + c) * npx + n];
    }

    __shared__ alignas(16) double lcb[CHUNK * C];
    __shared__ double lc2[CHUNK];

    double best[TPT]; int bi[TPT];
    #pragma unroll
    for (int t = 0; t < TPT; ++t) { best[t] = 1e300; bi[t] = 0; }

    for (int ch = 0; ch < cps; ch += CHUNK) {
        __syncthreads();
        const float* src = cb + (size_t)(seg_base + ch) * C;
        #pragma unroll
        for (int k = 0; k < (CHUNK * C) / 256; ++k) {
            int e = tid + k * 256;
            lcb[e] = (double)src[e];
        }
        if (tid < CHUNK) lc2[tid] = c2[seg_base + ch + tid];
        __syncthreads();

        for (int v = 0; v < CHUNK; ++v) {
            double aA[TPT], aB[TPT];
            #pragma unroll
            for (int t = 0; t < TPT; ++t) { aA[t] = 0.0; aB[t] = 0.0; }
            #pragma unroll
            for (int j2 = 0; j2 < 8; ++j2) {
                double2 ca = *reinterpret_cast<const double2*>(&lcb[v * C + 2 * j2]);
                double2 cB = *reinterpret_cast<const double2*>(&lcb[v * C + 16 + 2 * j2]);
                #pragma unroll
                for (int t = 0; t < TPT; ++t) {
                    aA[t] = fma(ca.y, zd[t][2 * j2 + 1], fma(ca.x, zd[t][2 * j2], aA[t]));
                    aB[t] = fma(cB.y, zd[t][16 + 2 * j2 + 1], fma(cB.x, zd[t][16 + 2 * j2], aB[t]));
                }
            }
            double cv = lc2[v];
            int vg = seg_base + ch + v;
            #pragma unroll
            for (int t = 0; t < TPT; ++t) {
                double s = fma(-2.0, aA[t] + aB[t], cv);
                if (s < best[t]) { best[t] = s; bi[t] = vg; }  // ascending vg: strict < keeps lowest idx on tie
            }
        }
    }
    int TP = nblk_tok * 256 * TPT;
    #pragma unroll
    for (int t = 0; t < TPT; ++t)
        if (tokv[t] < total) {
            pscore[(size_t)seg * TP + tokv[t]] = best[t];
            pidx [(size_t)seg * TP + tokv[t]] = bi[t];
        }
}

// combine per-segment argmins -> final index per token
__global__ void quantize_combine_kernel(const double* __restrict__ ps, const int* __restrict__ pi_,
                                        int* __restrict__ idxf, int total, int nseg, int TP) {
    int tok = blockIdx.x * 256 + threadIdx.x;
    if (tok >= total) return;
    double best = ps[tok]; int bi = pi_[tok];
    for (int s = 1; s < nseg; ++s) {
        double sc = ps[(size_t)s * TP + tok];
        if (sc < best) { best = sc; bi = pi_[(size_t)s * TP + tok]; }  // ascending seg: tie keeps lowest idx
    }
    idxf[tok] = bi;
}

// fused stage tail: gather -> bicubic up -> conv3x3 -> blend/update -> context pool -> next-z pool
__global__ __launch_bounds__(256) void stage_tail_kernel(
    const int* __restrict__ idxf, const float* __restrict__ cb,
    const float* __restrict__ w, const float* __restrict__ bias,
    float* __restrict__ f_hat, float* __restrict__ f_rest,
    float* __restrict__ out, float* __restrict__ znext,
    int pn, int off, int pn2)
{
    int bb = blockIdx.x >> 1;
    int og = (blockIdx.x & 1) * 16;
    int tid = threadIdx.x;
    int npx = pn * pn;

    __shared__ float h_s[32][257];   // hard embeddings; later overlaid by fh_s/fr_s
    __shared__ float hu_s[32][257];  // upsampled 16x16 per channel
    float (*fh_s)[257] = &h_s[0];
    float (*fr_s)[257] = &h_s[16];

    // 1) gather hard embeddings h[c][n] = cb[idx[n]][c]
    for (int e = tid; e < 32 * npx; e += 256) {
        int c = e & 31, n = e >> 5;
        int vb = idxf[bb * npx + n];
        h_s[c][n] = cb[vb * 32 + c];
    }
    __syncthreads();

    // 2) bicubic upsample pn x pn -> 16 x 16 (identity when pn==16)
    int p = tid >> 4, q = tid & 15;
    {
        float scale = (float)pn * (1.f / 16.f);
        float srcp = (p + 0.5f) * scale - 0.5f;
        float srcq = (q + 0.5f) * scale - 0.5f;
        int fp_ = (int)floorf(srcp), fq_ = (int)floorf(srcq);
        float tp = srcp - (float)fp_, tq = srcq - (float)fq_;
        float wp[4], wq[4];
        int ip[4], iq[4];
        #pragma unroll
        for (int k = 0; k < 4; ++k) {
            wp[k] = cubicw((float)(k - 1) - tp);
            wq[k] = cubicw((float)(k - 1) - tq);
            ip[k] = min(max(fp_ + k - 1, 0), pn - 1);
            iq[k] = min(max(fq_ + k - 1, 0), pn - 1);
        }
        for (int i = 0; i < 32; ++i) {
            float s = 0.f;
            #pragma unroll
            for (int kp = 0; kp < 4; ++kp) {
                float sr = 0.f;
                #pragma unroll
                for (int kq = 0; kq < 4; ++kq)
                    sr = fmaf(wq[kq], h_s[i][ip[kp] * pn + iq[kq]], sr);
                s = fmaf(wp[kp], sr, s);
            }
            hu_s[i][tid] = s;
        }
    }
    __syncthreads();

    // 3) conv 3x3 SAME over 32 in-ch for out-ch og..og+15 (w reads are wave-uniform -> scalar loads)
    float acc[16];
    #pragma unroll
    for (int o = 0; o < 16; ++o) acc[o] = bias[og + o];
    for (int i = 0; i < 32; ++i) {
        float v[9];
        #pragma unroll
        for (int dy = 0; dy < 3; ++dy)
            #pragma unroll
            for (int dx = 0; dx < 3; ++dx) {
                int pp = p + dy - 1, qq = q + dx - 1;
                bool in = (pp >= 0) & (pp < 16) & (qq >= 0) & (qq < 16);
                v[dy * 3 + dx] = in ? hu_s[i][pp * 16 + qq] : 0.f;
            }
        #pragma unroll
        for (int o = 0; o < 16; ++o) {
            const float* wp_ = w + ((og + o) * 32 + i) * 9;
            #pragma unroll
            for (int k = 0; k < 9; ++k) acc[o] = fmaf(wp_[k], v[k], acc[o]);
        }
    }

    // 4) blend + update f_hat/f_rest, stage new values into LDS (overlay on h_s, safe: h_s dead)
    #pragma unroll
    for (int o = 0; o < 16; ++o) {
        int gi = (bb * 32 + og + o) * 256 + tid;
        float hu = hu_s[og + o][tid];
        float blend = 0.5f * hu + 0.5f * acc[o];
        float nf = f_hat[gi] + blend;
        float nr = f_rest[gi] - blend;
        f_hat[gi] = nf; f_rest[gi] = nr;
        fh_s[o][tid] = nf; fr_s[o][tid] = nr;
    }
    __syncthreads();

    // 5) context: area-pool new f_hat to pn x pn, write transposed slice of out [B,680,C]
    for (int e = tid; e < 16 * npx; e += 256) {
        int o = e & 15, n = e >> 4;
        int y = n / pn, x = n - y * pn;
        int sh = (y * HH) / pn, eh = ((y + 1) * HH + pn - 1) / pn;
        int sw = (x * HH) / pn, ew = ((x + 1) * HH + pn - 1) / pn;
        float s = 0.f;
        for (int yy = sh; yy < eh; ++yy)
            for (int xx = sw; xx < ew; ++xx) s += fh_s[o][yy * 16 + xx];
        out[((bb * 680) + off + n) * 32 + og + o] = s * (1.f / (float)((eh - sh) * (ew - sw)));
    }

    // 6) next-stage z: area-pool new f_rest to pn2 x pn2
    if (pn2 > 0) {
        int npx2 = pn2 * pn2;
        for (int e = tid; e < 16 * npx2; e += 256) {
            int o = e / npx2, n = e - o * npx2;
            int y = n / pn2, x = n - y * pn2;
            int sh = (y * HH) / pn2, eh = ((y + 1) * HH + pn2 - 1) / pn2;
            int sw = (x * HH) / pn2, ew = ((x + 1) * HH + pn2 - 1) / pn2;
            float s = 0.f;
            for (int yy = sh; yy < eh; ++yy)
                for (int xx = sw; xx < ew; ++xx) s += fr_s[o][yy * 16 + xx];
            znext[(bb * 32 + og + o) * npx2 + n] = s * (1.f / (float)((eh - sh) * (ew - sw)));
        }
    }
}

// ---------------- launch ----------------

extern "C" void kernel_launch(void* const* d_in, const int* in_sizes, int n_in,
                              void* d_out, int out_size, void* d_ws, size_t ws_size,
                              hipStream_t stream) {
    const float* feat = (const float*)d_in[0];
    const float* cb   = (const float*)d_in[1];
    const float* phiw = (const float*)d_in[2];
    const float* phib = (const float*)d_in[3];
    float* out = (float*)d_out;
    float* wsf = (float*)d_ws;

    const int NE = B * C * HH * HH; // 1048576
    float* f_rest = wsf;
    float* f_hat  = wsf + NE;
    float* zbuf   = wsf + 2 * NE;
    char*  tail   = (char*)(wsf + 3 * NE);
    double* c2     = (double*)tail;                                   // 32 KB
    double* pscore = (double*)(tail + (32 << 10));                    // 3.5 MB (max 409600 doubles)
    int*    pidx   = (int*)   (tail + (32 << 10) + 3670016);          // 2 MB
    int*    idxf   = (int*)   (tail + (32 << 10) + 3670016 + (2 << 20)); // 128 KB

    static const int PN_[10]   = {1, 2, 3, 4, 5, 6, 8, 10, 13, 16};
    static const int PI_[10]   = {0, 0, 1, 1, 1, 2, 2, 2, 3, 3};
    static const int OFF_[10]  = {0, 1, 5, 14, 30, 55, 91, 155, 255, 424};
    static const int NSEG_[10] = {32, 32, 32, 32, 32, 32, 32, 32, 16, 8};
    static const int TPT_[10]  = {1, 1, 1, 1, 1, 1, 2, 2, 2, 2};

    init_kernel<<<dim3((NE + 255) / 256), dim3(256), 0, stream>>>(feat, f_rest, f_hat);
    c2_kernel<<<dim3(V / 256), dim3(256), 0, stream>>>(cb, c2);
    // stage-0 z from initial f_rest (= feat)
    area_down_kernel<<<dim3((B * C + 255) / 256), dim3(256), 0, stream>>>(f_rest, zbuf, 1);

    for (int si = 0; si < 10; ++si) {
        int pn = PN_[si], npx = pn * pn;
        int tokens = B * npx;
        int tpt = TPT_[si], nseg = NSEG_[si];
        int nblk_tok = (tokens + 256 * tpt - 1) / (256 * tpt);
        int TP = nblk_tok * 256 * tpt;

        if (tpt == 1)
            quantize_scan_kernel<1><<<dim3(nblk_tok * nseg), dim3(256), 0, stream>>>(
                zbuf, cb, c2, pscore, pidx, npx, nseg, nblk_tok);
        else
            quantize_scan_kernel<2><<<dim3(nblk_tok * nseg), dim3(256), 0, stream>>>(
                zbuf, cb, c2, pscore, pidx, npx, nseg, nblk_tok);

        quantize_combine_kernel<<<dim3((tokens + 255) / 256), dim3(256), 0, stream>>>(
            pscore, pidx, idxf, tokens, nseg, TP);

        int pn2 = (si < 9) ? PN_[si + 1] : 0;
        stage_tail_kernel<<<dim3(B * 2), dim3(256), 0, stream>>>(
            idxf, cb, phiw + PI_[si] * C * C * 9, phib + PI_[si] * C,
            f_hat, f_rest, out, zbuf, pn, OFF_[si], pn2);
    }
}